// Round 2
// baseline (514.357 us; speedup 1.0000x reference)
//
#include <hip/hip_runtime.h>

// PartialProductAccumulator — v3 = v2 + DIAGNOSTIC duplicate read stream.
// MEASUREMENT ROUND: the harness top-5 only shows ~236us poison fills, so the
// kernel's own duration is unobservable; dur_us deltas are the only probe.
// This version keeps the verified v2 compute path BIT-IDENTICAL and adds a
// second, plane-offset ((q+27)%54) read stream of the same windows into a
// dummy accumulator (kept live via asm sink, rule #17 anti-DCE). Input is
// read exactly 2x; the 27-plane offset puts >=368MB of traffic between
// re-reads of any line, defeating L3 (256MB) whether or not nt suppresses
// allocation. dur_us_new - dur_us_old ~= R, the current kernel's read time:
//   ~+65-80us  -> reads already near 6.3TB/s roofline -> declare ROOFLINE
//   ~+100-130  -> reads at ~3.9TB/s -> ~50us headroom, pursue
//   ~+210+     -> reads at ~1.7TB/s -> large headroom, thrash real
//   <+40       -> dup stream got cache-served/DCE'd -> inspect disasm

#define N_PP   54
#define BITS   108
#define BATCH  16384
#define ROW_F4 (BITS / 4)                    // 27 float4 per row
#define PLANE_F4 ((size_t)BATCH * ROW_F4)    // 442368 float4 per p-plane
#define TPB     432                          // threads per block
#define CPT     2                            // float4 chunks per thread per plane
#define BLK_F4  (TPB * CPT)                  // 864 f4 per block per plane
#define ROWS_PB (BLK_F4 / ROW_F4)            // 32 batch rows per block
#define GRID    ((int)(PLANE_F4 / BLK_F4))   // 512 blocks

typedef float vf4 __attribute__((ext_vector_type(4)));

__global__ __launch_bounds__(TPB)
void ppacc_fused(const vf4* __restrict__ pps, vf4* __restrict__ out) {
    __shared__ float counts[ROWS_PB][BITS + 1];   // stride 109 = 13 mod 32

    const int tid = threadIdx.x;
    const size_t base = (size_t)blockIdx.x * BLK_F4 + tid;
    const vf4* p = pps + base;                    // chunk0; chunk1 at +TPB

    // ---- phase 1: column popcount, 1-plane-deep pipeline (REAL path) ----
    vf4 acc0 = (vf4)(0.f), acc1 = (vf4)(0.f);

    vf4 a0 = __builtin_nontemporal_load(p);
    vf4 a1 = __builtin_nontemporal_load(p + TPB);
    vf4 b0 = __builtin_nontemporal_load(p + PLANE_F4);
    vf4 b1 = __builtin_nontemporal_load(p + PLANE_F4 + TPB);

    // ---- DIAGNOSTIC dup stream: planes (q+27)%54, same windows ----
    vf4 dacc0 = (vf4)(0.f), dacc1 = (vf4)(0.f);
    const vf4* pdq = p + (size_t)27 * PLANE_F4;   // opaque base, defeats CSE
    asm volatile("" : "+v"(pdq));
    vf4 da0 = __builtin_nontemporal_load(pdq);                  // plane 27
    vf4 da1 = __builtin_nontemporal_load(pdq + TPB);
    vf4 db0 = __builtin_nontemporal_load(pdq + PLANE_F4);       // plane 28
    vf4 db1 = __builtin_nontemporal_load(pdq + PLANE_F4 + TPB);

    const vf4* pn  = p   + 2 * PLANE_F4;          // main cursor: plane q+2
    const vf4* pdl = pdq + 2 * PLANE_F4;          // dup cursor: plane (q+2+27)%54
#pragma unroll 4
    for (int q = 0; q < N_PP - 2; ++q) {          // consume planes 0..51
        vf4 c0 = __builtin_nontemporal_load(pn);
        vf4 c1 = __builtin_nontemporal_load(pn + TPB);
        pn += PLANE_F4;
        vf4 dc0 = __builtin_nontemporal_load(pdl);
        vf4 dc1 = __builtin_nontemporal_load(pdl + TPB);
        pdl += PLANE_F4;
        if (q == 24) pdl -= (size_t)N_PP * PLANE_F4;   // wrap plane 54 -> 0
        acc0 += a0; acc1 += a1;
        a0 = b0; a1 = b1;
        b0 = c0; b1 = c1;
        dacc0 += da0; dacc1 += da1;
        da0 = db0; da1 = db1;
        db0 = dc0; db1 = dc1;
    }
    acc0 += a0; acc1 += a1;                       // plane 52
    acc0 += b0; acc1 += b1;                       // plane 53
    dacc0 += da0; dacc1 += da1;
    dacc0 += db0; dacc1 += db1;

    // keep the dup stream live without affecting results (rule #17)
    asm volatile("" :: "v"(dacc0.x), "v"(dacc0.y), "v"(dacc0.z), "v"(dacc0.w),
                       "v"(dacc1.x), "v"(dacc1.y), "v"(dacc1.z), "v"(dacc1.w));

    // ---- phase 2: carry propagation through LDS (unchanged from v2) ----
    const int rr = tid / ROW_F4;                  // 0..15 (chunk0 row)
    const int bb = (tid % ROW_F4) * 4;            // bit column base
    counts[rr][bb + 0] = acc0.x;
    counts[rr][bb + 1] = acc0.y;
    counts[rr][bb + 2] = acc0.z;
    counts[rr][bb + 3] = acc0.w;
    counts[rr + 16][bb + 0] = acc1.x;             // chunk1 row = rr + 16
    counts[rr + 16][bb + 1] = acc1.y;
    counts[rr + 16][bb + 2] = acc1.z;
    counts[rr + 16][bb + 3] = acc1.w;
    __syncthreads();

    if (tid < ROWS_PB) {
        int c = 0;
#pragma unroll
        for (int i = 0; i < BITS; ++i) {
            const int t = (int)counts[tid][i] + c;
            counts[tid][i] = (float)(t & 1);
            c = t >> 1;                           // carry out of bit 107 dropped
        }
    }
    __syncthreads();

    {
        vf4 v0, v1;
        v0.x = counts[rr][bb + 0];
        v0.y = counts[rr][bb + 1];
        v0.z = counts[rr][bb + 2];
        v0.w = counts[rr][bb + 3];
        v1.x = counts[rr + 16][bb + 0];
        v1.y = counts[rr + 16][bb + 1];
        v1.z = counts[rr + 16][bb + 2];
        v1.w = counts[rr + 16][bb + 3];
        __builtin_nontemporal_store(v0, out + base);
        __builtin_nontemporal_store(v1, out + base + TPB);
    }
}

extern "C" void kernel_launch(void* const* d_in, const int* in_sizes, int n_in,
                              void* d_out, int out_size, void* d_ws, size_t ws_size,
                              hipStream_t stream) {
    const vf4* pps = (const vf4*)d_in[0];
    vf4* out = (vf4*)d_out;
    ppacc_fused<<<GRID, TPB, 0, stream>>>(pps, out);
}